// Round 9
// baseline (130.818 us; speedup 1.0000x reference)
//
#include <hip/hip_runtime.h>

#define NN 768
#define IN_F 68
#define KNN 8
#define EO 32
#define FEAT 264
#define HALF_FEAT 132
#define EMB 32
#define NPAIR 294528   // 768*767/2

typedef __attribute__((ext_vector_type(8))) short bf16x8;
typedef __attribute__((ext_vector_type(4))) float f32x4;

// pack hi16(x1):hi16(x0) into one dword — bf16 truncation of two floats, 1 v_perm
static __device__ __forceinline__ int pack_chop2(float x0, float x1) {
  return __builtin_amdgcn_perm(__float_as_uint(x1), __float_as_uint(x0), 0x07060302);
}
static __device__ __forceinline__ float chop(float x) {
  return __uint_as_float(__float_as_uint(x) & 0xffff0000u);
}

// Session ledger (MI355X, measured r1-r8):
//   grid barrier (any impl): 230-400us @1538 blocks -> never use
//   cross-XCD i64 atomics:   ~60us per ~600K RMWs   -> never bulk-use
//   kernel boundary:         ~5-15us                -> cheapest sync
//   fusion-by-recompute with 49x redundancy (D into E): +20us -> reverted
//   coalesced f32x4 weight loads (r8): -3.8us; kernels are latency-floor bound
// This round: cut A's serial merge critical path (butterfly merge network,
// registers-only) and halve E's per-block fixed overhead (16x32 tiles).

// merge two ascending sorted 8-lists, keep the smallest 8 (ascending).
// Standard bitonic half-cleaner + 3-stage cleaner; fully unrolled, reg-only.
static __device__ __forceinline__ void merge8(unsigned long long k[8],
                                              const unsigned long long o[8]) {
  unsigned long long m[8];
#pragma unroll
  for (int x = 0; x < 8; x++) {
    unsigned long long a = k[x], b = o[7-x];
    m[x] = a < b ? a : b;
  }
#define CSW(p,qq) { unsigned long long lo = m[p]<m[qq]?m[p]:m[qq]; \
                    unsigned long long hi = m[p]<m[qq]?m[qq]:m[p]; \
                    m[p]=lo; m[qq]=hi; }
  CSW(0,4) CSW(1,5) CSW(2,6) CSW(3,7)
  CSW(0,2) CSW(1,3) CSW(4,6) CSW(5,7)
  CSW(0,1) CSW(2,3) CSW(4,5) CSW(6,7)
#undef CSW
#pragma unroll
  for (int x = 0; x < 8; x++) k[x] = m[x];
}

// ---------------- Kernel A: top-8 neighbors + EdgeConv1 (2 waves) ----------
__global__ void __launch_bounds__(128) topk_ec1_kernel(
    const float* __restrict__ feat0, const float* __restrict__ feat1,
    const float* __restrict__ w1, const float* __restrict__ b1,
    const float* __restrict__ w2, const float* __restrict__ b2,
    int* __restrict__ idx_out, float* __restrict__ e1out)
{
  const int i = blockIdx.x, g = blockIdx.y;
  const float* __restrict__ feat = g ? feat1 : feat0;
  const int tid = threadIdx.x;
  const int lane = tid & 63, wv = tid >> 6;

  __shared__ int nbr[8];
  __shared__ unsigned long long xk[2][8];
  __shared__ float gl[KNN*IN_F];
  __shared__ float hsh[EO];
  __shared__ f32x4 part1[16][8];   // [sub][eg]
  __shared__ f32x4 part2[16][8];

  const float4 ci = *(const float4*)(feat + i*IN_F);

  float4 cand[6];
#pragma unroll
  for (int t = 0; t < 6; t++)
    cand[t] = *(const float4*)(feat + (tid + 128*t)*IN_F);

  float bd[8]; int bidx[8];
#pragma unroll
  for (int k = 0; k < 8; k++) { bd[k] = 1e30f; bidx[k] = 0; }
#pragma unroll
  for (int t = 0; t < 6; t++) {
    const int j = tid + 128*t;
    float d = fabsf(ci.x - cand[t].x);   // same sequential add order as ref sum(-1)
    d += fabsf(ci.y - cand[t].y);
    d += fabsf(ci.z - cand[t].z);
    d += fabsf(ci.w - cand[t].w);
    if (d < bd[7]) {
#pragma unroll
      for (int k = 7; k >= 1; k--) {
        if (d < bd[k-1])    { bd[k] = bd[k-1]; bidx[k] = bidx[k-1]; }
        else if (d < bd[k]) { bd[k] = d;       bidx[k] = j; }
      }
      if (d < bd[0]) { bd[0] = d; bidx[0] = j; }
    }
  }

  // per-thread sorted-8 keys in registers (ascending; unique among reals)
  unsigned long long key[8];
#pragma unroll
  for (int k = 0; k < 8; k++)
    key[k] = ((unsigned long long)__float_as_uint(bd[k]) << 32) | (unsigned)bidx[k];

  // intra-wave butterfly all-reduce merge: 6 levels, shfls independent
#pragma unroll
  for (int s = 1; s < 64; s <<= 1) {
    unsigned long long ok[8];
#pragma unroll
    for (int x = 0; x < 8; x++) ok[x] = __shfl_xor(key[x], s, 64);
    merge8(key, ok);
  }
  // cross-wave merge via LDS (each wave holds top-8 of its half)
  if (lane == 0) {
#pragma unroll
    for (int x = 0; x < 8; x++) xk[wv][x] = key[x];
  }
  __syncthreads();
  {
    unsigned long long ok[8];
#pragma unroll
    for (int x = 0; x < 8; x++) ok[x] = xk[wv^1][x];
    merge8(key, ok);
  }
  if (tid == 0) {
#pragma unroll
    for (int k = 0; k < 8; k++) {
      int nb = (int)(key[k] & 0xffffffffull);
      nbr[k] = nb;
      idx_out[(g*NN+i)*8 + k] = nb;
    }
  }
  __syncthreads();

  for (int z = tid; z < KNN*17; z += 128) {
    int k = z / 17, q = z - k*17;
    *(float4*)&gl[k*IN_F + q*4] = *(const float4*)(feat + nbr[k]*IN_F + q*4);
  }
  __syncthreads();

  // ---- layer1, coalesced float4 weight loads ----
  const int eg = tid & 7, sub = tid >> 3;
  {
    f32x4 a4 = {0.f,0.f,0.f,0.f};
    const float* wp = w1 + eg*4;
    for (int t = 0; t < 34; t++) {
      const int r = sub + 16*t;
      const int k = r & 7, c = r >> 3;
      const float s = gl[k*IN_F + c];
      a4 += s * *(const f32x4*)(wp + r*EO);
    }
    part1[sub][eg] = a4;
  }
  __syncthreads();
  if (tid < 32) {
    float h = b1[tid];
    const float* pp = (const float*)part1;   // [sub][eg][cm] = sub*32 + e
#pragma unroll
    for (int s = 0; s < 16; s++) h += pp[s*32 + tid];
    hsh[tid] = fmaxf(h, 0.01f*h);
  }
  __syncthreads();

  // ---- layer2 ----
  {
    const int m0 = sub*2;
    f32x4 a4 = hsh[m0]   * *(const f32x4*)(w2 + (m0+0)*EO + eg*4)
             + hsh[m0+1] * *(const f32x4*)(w2 + (m0+1)*EO + eg*4);
    part2[sub][eg] = a4;
  }
  __syncthreads();
  if (tid < 32) {
    float o = b2[tid];
    const float* pp = (const float*)part2;
#pragma unroll
    for (int s = 0; s < 16; s++) o += pp[s*32 + tid];
    o = fmaxf(o, 0.01f*o);
    e1out[(g*NN+i)*EO + tid] = o;
  }
}

// ---------------- Kernel B: EdgeConv2 (coalesced float4 weights) ----------
__global__ void __launch_bounds__(64) ec2_kernel(
    const int* __restrict__ idx, const float* __restrict__ e1,
    const float* __restrict__ w1, const float* __restrict__ b1,
    const float* __restrict__ w2, const float* __restrict__ b2,
    float* __restrict__ e2out)
{
  const int i = blockIdx.x, g = blockIdx.y;
  const int lane = threadIdx.x;
  __shared__ float gl[KNN*36];     // stride 36: kills 8-way bank conflict
  __shared__ float hsh[EO];
  __shared__ f32x4 partb[8][8];
  {
    const int k = lane >> 3, q = lane & 7;
    const int nb = idx[(g*NN+i)*8 + k];
    *(float4*)&gl[k*36 + q*4] = *(const float4*)(e1 + (g*NN+nb)*EO + q*4);
  }
  __syncthreads();
  const int eg = lane & 7, sub = lane >> 3;
  {
    f32x4 a4 = {0.f,0.f,0.f,0.f};
    const float* wp = w1 + eg*4;
    for (int t = 0; t < 32; t++) {
      const int r = sub + 8*t;           // k = sub, c = t
      const float s = gl[sub*36 + t];
      a4 += s * *(const f32x4*)(wp + r*EO);
    }
    partb[sub][eg] = a4;
  }
  __syncthreads();
  if (lane < 32) {
    float h = b1[lane];
    const float* pp = (const float*)partb;
#pragma unroll
    for (int s = 0; s < 8; s++) h += pp[s*32 + lane];
    hsh[lane] = fmaxf(h, 0.01f*h);
  }
  __syncthreads();
  {
    f32x4 a4 = {0.f,0.f,0.f,0.f};
#pragma unroll
    for (int j = 0; j < 4; j++) {
      const int m = sub*4 + j;
      a4 += hsh[m] * *(const f32x4*)(w2 + m*EO + eg*4);
    }
    partb[sub][eg] = a4;
  }
  __syncthreads();
  if (lane < 32) {
    float o = b2[lane];
    const float* pp = (const float*)partb;
#pragma unroll
    for (int s = 0; s < 8; s++) o += pp[s*32 + lane];
    o = fmaxf(o, 0.01f*o);
    e2out[(g*NN+i)*EO + lane] = o;
  }
}

// ---------------- Kernel C: BN stats (unchanged) ----------------
__global__ void __launch_bounds__(256) stats_kernel(
    const float* __restrict__ feat0, const float* __restrict__ feat1,
    const float* __restrict__ e1, const float* __restrict__ e2,
    const float* __restrict__ bn_g,
    float* __restrict__ mu_out, float* __restrict__ sg_out)
{
  const int c = blockIdx.x;   // 0..131
  const int tid = threadIdx.x;
  double s1=0, s2=0, q1=0, q2=0;
  for (int t = tid; t < 2*NN; t += 256) {
    int g = t >= NN;
    int i = t - g*NN;
    float val;
    if (c < IN_F)      val = (g ? feat1 : feat0)[i*IN_F + c];
    else if (c < 100)  val = e1[(g*NN+i)*EO + (c-IN_F)];
    else               val = e2[(g*NN+i)*EO + (c-100)];
    double dv = val;
    double wf = (double)(NN-1-i), wsnd = (double)i;
    s1 += wf*dv;  s2 += wsnd*dv;
    double dq = dv*dv;
    q1 += wf*dq;  q2 += wsnd*dq;
  }
#pragma unroll
  for (int off = 32; off >= 1; off >>= 1) {
    s1 += __shfl_xor(s1, off, 64);
    s2 += __shfl_xor(s2, off, 64);
    q1 += __shfl_xor(q1, off, 64);
    q2 += __shfl_xor(q2, off, 64);
  }
  __shared__ double red[4][4];
  const int w = tid >> 6;
  if ((tid & 63) == 0) { red[w][0]=s1; red[w][1]=s2; red[w][2]=q1; red[w][3]=q2; }
  __syncthreads();
  if (tid == 0) {
    double t0 = red[0][0]+red[1][0]+red[2][0]+red[3][0];
    double t1 = red[0][1]+red[1][1]+red[2][1]+red[3][1];
    double t2 = red[0][2]+red[1][2]+red[2][2]+red[3][2];
    double t3 = red[0][3]+red[1][3]+red[2][3]+red[3][3];
    const double M2 = 2.0 * (double)NPAIR;
    double mu1 = t0/M2, mu2 = t1/M2;
    double v1 = t2/M2 - mu1*mu1;
    double v2 = t3/M2 - mu2*mu2;
    mu_out[c]           = (float)mu1;
    mu_out[HALF_FEAT+c] = (float)mu2;
    sg_out[c]           = (float)((double)bn_g[c] / sqrt(v1 + 1e-5));
    sg_out[HALF_FEAT+c] = (float)((double)bn_g[HALF_FEAT+c] / sqrt(v2 + 1e-5));
  }
}

// ---------------- Kernel D: per-node u/v + c0 (coalesced float4 weights) --
__global__ void __launch_bounds__(64) uv_c0_kernel(
    const float* __restrict__ feat0, const float* __restrict__ feat1,
    const float* __restrict__ e1, const float* __restrict__ e2,
    const float* __restrict__ sg, const float* __restrict__ mu,
    const float* __restrict__ bn_b,
    const float* __restrict__ lin1_w, const float* __restrict__ lin1_b,
    float* __restrict__ u, float* __restrict__ v, float* __restrict__ c0g)
{
  const int i = blockIdx.x, g = blockIdx.y;
  const int t = threadIdx.x;
  if (i == NN) {
    if (g == 0 && t < EMB) {
      float a0=0.f, a1=0.f, a2=0.f, a3=0.f;
      for (int c = 0; c < FEAT; c += 4) {
        a0 += (bn_b[c+0] - mu[c+0]*sg[c+0]) * lin1_w[(c+0)*EMB + t];
        a1 += (bn_b[c+1] - mu[c+1]*sg[c+1]) * lin1_w[(c+1)*EMB + t];
        a2 += (bn_b[c+2] - mu[c+2]*sg[c+2]) * lin1_w[(c+2)*EMB + t];
        a3 += (bn_b[c+3] - mu[c+3]*sg[c+3]) * lin1_w[(c+3)*EMB + t];
      }
      c0g[t] = lin1_b[t] + ((a0+a1)+(a2+a3));
    }
    return;
  }
  __shared__ float x[HALF_FEAT];
  __shared__ f32x4 partd[8][8];
  for (int c = t; c < IN_F; c += 64) x[c] = (g ? feat1 : feat0)[i*IN_F + c];
  if (t < 32) x[IN_F + t]     = e1[(g*NN+i)*EO + t];
  else        x[100 + (t-32)] = e2[(g*NN+i)*EO + (t-32)];
  __syncthreads();
  const int eg = t & 7, sub = t >> 3;
  {
    f32x4 a4 = {0.f,0.f,0.f,0.f};
    const int roff = (sub >= 4) ? HALF_FEAT : 0;
    const float* wp = lin1_w + eg*4;
    for (int tt = 0; tt < 33; tt++) {
      const int r = sub*33 + tt;
      const float xv = x[r - roff] * sg[r];
      a4 += xv * *(const f32x4*)(wp + r*EMB);
    }
    partd[sub][eg] = a4;
  }
  __syncthreads();
  const float* pp = (const float*)partd;   // [sub][eg][cm] = sub*32 + e
  if (t < 32) {
    float acc = (pp[0*32+t] + pp[1*32+t]) + (pp[2*32+t] + pp[3*32+t]);
    u[(g*NN+i)*EMB + t] = acc;
  } else {
    const int e = t - 32;
    float acc = (pp[4*32+e] + pp[5*32+e]) + (pp[6*32+e] + pp[7*32+e]);
    v[(g*NN+i)*EMB + e] = acc;
  }
}

// ---------------- Kernel E: pair MLP, 16x32 tiles (split-bf16 MFMA) -------
// Each block: a-tile (16 i-rows) x B2 (32 j-cols). Triangle covered exactly
// once by a <= 2*B2+1 (600 blocks/graph vs 1176): per-block fixed overhead
// (weight load/pack, su staging) amortized over 2x output.
__global__ void __launch_bounds__(256) pair_kernel(
    const float* __restrict__ u, const float* __restrict__ v,
    const float* __restrict__ c0g,
    const float* __restrict__ lin2_w, const float* __restrict__ lin2_b,
    const float* __restrict__ lin3_w, const float* __restrict__ lin3_b,
    float2* __restrict__ out)
{
  const int g = blockIdx.y;
  int rem = blockIdx.x;        // 0..599
  int B2 = 0;
  for (;;) {
    int cnt = 2*B2 + 2; if (cnt > 48) cnt = 48;
    if (rem < cnt) break;
    rem -= cnt; B2++;
  }
  const int a = rem;           // a*16 rows; B2*32 cols

  __shared__ float su[16*36], sv[32*36];
  __shared__ float wbuf[4][32*36];
  const int tid = threadIdx.x;
  {
    const int r = tid >> 5, c = tid & 31;      // r 0..7
    su[r*36+c]      = u[(g*NN + a*16 + r)*EMB + c];
    su[(r+8)*36+c]  = u[(g*NN + a*16 + r+8)*EMB + c];
    sv[r*36+c]      = v[(g*NN + B2*32 + r)*EMB + c];
    sv[(r+8)*36+c]  = v[(g*NN + B2*32 + r+8)*EMB + c];
    sv[(r+16)*36+c] = v[(g*NN + B2*32 + r+16)*EMB + c];
    sv[(r+24)*36+c] = v[(g*NN + B2*32 + r+24)*EMB + c];
  }
  __syncthreads();

  const int lane = tid & 63, w = tid >> 6;
  const int q = lane & 15, kg = lane >> 4;   // q: m/n index, kg: k-group

  union { int i[4]; bf16x8 v; } whi0, wlo0, whi1, wlo1;
#pragma unroll
  for (int d = 0; d < 4; d++) {
    float w0a = lin2_w[(kg*8+2*d)*32 + q];
    float w0b = lin2_w[(kg*8+2*d+1)*32 + q];
    float w1a = lin2_w[(kg*8+2*d)*32 + 16 + q];
    float w1b = lin2_w[(kg*8+2*d+1)*32 + 16 + q];
    whi0.i[d] = pack_chop2(w0a, w0b);
    wlo0.i[d] = pack_chop2(w0a - chop(w0a), w0b - chop(w0b));
    whi1.i[d] = pack_chop2(w1a, w1b);
    wlo1.i[d] = pack_chop2(w1a - chop(w1a), w1b - chop(w1b));
  }
  float svc0[8], svc1[8];
#pragma unroll
  for (int jj = 0; jj < 8; jj++) {
    const float c0 = c0g[kg*8+jj];
    svc0[jj] = sv[q*36 + kg*8 + jj] + c0;
    svc1[jj] = sv[(16+q)*36 + kg*8 + jj] + c0;
  }
  float2 w3v[8]; float b2v[8];
#pragma unroll
  for (int jj = 0; jj < 8; jj++) {
    w3v[jj] = ((const float2*)lin3_w)[kg*8+jj];
    b2v[jj] = lin2_b[kg*8+jj];
  }
  const float b30 = lin3_b[0], b31 = lin3_b[1];

  float* wb = wbuf[w];
#pragma unroll
  for (int t = 0; t < 4; t++) {
    const int ty = w*4 + t;
    const float4 sa = *(const float4*)&su[ty*36 + kg*8];
    const float4 sb = *(const float4*)&su[ty*36 + kg*8 + 4];
    float se[8] = {sa.x, sa.y, sa.z, sa.w, sb.x, sb.y, sb.z, sb.w};
    union { int i[4]; bf16x8 v; } ahi0, alo0, ahi1, alo1;
#pragma unroll
    for (int d = 0; d < 4; d++) {
      float s0 = se[2*d]   + svc0[2*d];
      float s1 = se[2*d+1] + svc0[2*d+1];
      s0 = fmaxf(s0, 0.01f*s0);
      s1 = fmaxf(s1, 0.01f*s1);
      ahi0.i[d] = pack_chop2(s0, s1);
      alo0.i[d] = pack_chop2(s0 - chop(s0), s1 - chop(s1));
      float t0 = se[2*d]   + svc1[2*d];
      float t1 = se[2*d+1] + svc1[2*d+1];
      t0 = fmaxf(t0, 0.01f*t0);
      t1 = fmaxf(t1, 0.01f*t1);
      ahi1.i[d] = pack_chop2(t0, t1);
      alo1.i[d] = pack_chop2(t0 - chop(t0), t1 - chop(t1));
    }
    f32x4 acc00 = {0.f,0.f,0.f,0.f}, acc01 = {0.f,0.f,0.f,0.f};
    f32x4 acc10 = {0.f,0.f,0.f,0.f}, acc11 = {0.f,0.f,0.f,0.f};
    acc00 = __builtin_amdgcn_mfma_f32_16x16x32_bf16(ahi0.v, whi0.v, acc00, 0,0,0);
    acc01 = __builtin_amdgcn_mfma_f32_16x16x32_bf16(ahi0.v, whi1.v, acc01, 0,0,0);
    acc10 = __builtin_amdgcn_mfma_f32_16x16x32_bf16(ahi1.v, whi0.v, acc10, 0,0,0);
    acc11 = __builtin_amdgcn_mfma_f32_16x16x32_bf16(ahi1.v, whi1.v, acc11, 0,0,0);
    acc00 = __builtin_amdgcn_mfma_f32_16x16x32_bf16(ahi0.v, wlo0.v, acc00, 0,0,0);
    acc01 = __builtin_amdgcn_mfma_f32_16x16x32_bf16(ahi0.v, wlo1.v, acc01, 0,0,0);
    acc10 = __builtin_amdgcn_mfma_f32_16x16x32_bf16(ahi1.v, wlo0.v, acc10, 0,0,0);
    acc11 = __builtin_amdgcn_mfma_f32_16x16x32_bf16(ahi1.v, wlo1.v, acc11, 0,0,0);
    acc00 = __builtin_amdgcn_mfma_f32_16x16x32_bf16(alo0.v, whi0.v, acc00, 0,0,0);
    acc01 = __builtin_amdgcn_mfma_f32_16x16x32_bf16(alo0.v, whi1.v, acc01, 0,0,0);
    acc10 = __builtin_amdgcn_mfma_f32_16x16x32_bf16(alo1.v, whi0.v, acc10, 0,0,0);
    acc11 = __builtin_amdgcn_mfma_f32_16x16x32_bf16(alo1.v, whi1.v, acc11, 0,0,0);
#pragma unroll
    for (int r = 0; r < 4; r++) {
      wb[(kg*4+r)*36 + q]           = acc00[r];
      wb[(kg*4+r)*36 + 16 + q]      = acc01[r];
      wb[(16+kg*4+r)*36 + q]        = acc10[r];
      wb[(16+kg*4+r)*36 + 16 + q]   = acc11[r];
    }
    float o00 = 0.f, o01 = 0.f, o10 = 0.f, o11 = 0.f;
#pragma unroll
    for (int jj = 0; jj < 8; jj++) {
      float h0 = wb[q*36 + kg*8 + jj] + b2v[jj];
      h0 = fmaxf(h0, 0.01f*h0);
      o00 += h0 * w3v[jj].x;
      o01 += h0 * w3v[jj].y;
      float h1 = wb[(16+q)*36 + kg*8 + jj] + b2v[jj];
      h1 = fmaxf(h1, 0.01f*h1);
      o10 += h1 * w3v[jj].x;
      o11 += h1 * w3v[jj].y;
    }
    o00 += __shfl_xor(o00, 16, 64); o00 += __shfl_xor(o00, 32, 64);
    o01 += __shfl_xor(o01, 16, 64); o01 += __shfl_xor(o01, 32, 64);
    o10 += __shfl_xor(o10, 16, 64); o10 += __shfl_xor(o10, 32, 64);
    o11 += __shfl_xor(o11, 16, 64); o11 += __shfl_xor(o11, 32, 64);
    const int i = a*16 + ty;
    if (lane < 16) {
      const int j0 = B2*32 + q, j1 = B2*32 + 16 + q;
      if (j0 > i) {
        long p = (long)i*NN - (long)i*(i+1)/2 + (j0 - i - 1);
        out[(long)g*NPAIR + p] = make_float2(o00 + b30, o01 + b31);
      }
      if (j1 > i) {
        long p = (long)i*NN - (long)i*(i+1)/2 + (j1 - i - 1);
        out[(long)g*NPAIR + p] = make_float2(o10 + b30, o11 + b31);
      }
    }
  }
}

extern "C" void kernel_launch(void* const* d_in, const int* in_sizes, int n_in,
                              void* d_out, int out_size, void* d_ws, size_t ws_size,
                              hipStream_t stream)
{
  const float* feat0  = (const float*)d_in[0];
  const float* feat1  = (const float*)d_in[1];
  const float* ec1_w1 = (const float*)d_in[2];
  const float* ec1_b1 = (const float*)d_in[3];
  const float* ec1_w2 = (const float*)d_in[4];
  const float* ec1_b2 = (const float*)d_in[5];
  const float* ec2_w1 = (const float*)d_in[6];
  const float* ec2_b1 = (const float*)d_in[7];
  const float* ec2_w2 = (const float*)d_in[8];
  const float* ec2_b2 = (const float*)d_in[9];
  const float* bn_g   = (const float*)d_in[10];
  const float* bn_b   = (const float*)d_in[11];
  const float* lin1_w = (const float*)d_in[12];
  const float* lin1_b = (const float*)d_in[13];
  const float* lin2_w = (const float*)d_in[14];
  const float* lin2_b = (const float*)d_in[15];
  const float* lin3_w = (const float*)d_in[16];
  const float* lin3_b = (const float*)d_in[17];

  char* ws = (char*)d_ws;
  int*   idx = (int*)  (ws + 0);
  float* e1  = (float*)(ws + 49152);
  float* e2  = (float*)(ws + 245760);
  float* u   = (float*)(ws + 442368);
  float* v   = (float*)(ws + 638976);
  float* mu  = (float*)(ws + 835584);
  float* sg  = (float*)(ws + 836640);
  float* c0g = (float*)(ws + 837696);

  topk_ec1_kernel<<<dim3(768,2), 128, 0, stream>>>(feat0, feat1, ec1_w1, ec1_b1,
                                                   ec1_w2, ec1_b2, idx, e1);
  ec2_kernel<<<dim3(768,2), 64, 0, stream>>>(idx, e1, ec2_w1, ec2_b1,
                                             ec2_w2, ec2_b2, e2);
  stats_kernel<<<dim3(132), 256, 0, stream>>>(feat0, feat1, e1, e2, bn_g, mu, sg);
  uv_c0_kernel<<<dim3(769,2), 64, 0, stream>>>(feat0, feat1, e1, e2, sg, mu, bn_b,
                                               lin1_w, lin1_b, u, v, c0g);
  pair_kernel<<<dim3(600,2), 256, 0, stream>>>(u, v, c0g, lin2_w, lin2_b,
                                               lin3_w, lin3_b, (float2*)d_out);
}